// Round 7
// baseline (237.804 us; speedup 1.0000x reference)
//
#include <hip/hip_runtime.h>
#include <math.h>

// SCNCore: hidden = sigmoid((concept@Wci^T)*(x@Win^T) + (concept@Wcs^T)*(h@Wst^T))
//          i,f,o,cc = split(hidden,4); c_t = i*cc + f*c_state; h_t = o*tanh(c_t)
// B=1024, IN=H=1024, C=1000, 4H=4096. Inputs fp32, outputs fp32.
//
// R7: revert to R5's 48us GEMM structure; single change: A-operand held in
// registers, PREFETCHED +1 K-iteration (issued after barrier(i), consumed
// after barrier(i+1) -> full compute phase of latency slack). Kills sA writes
// + af LDS reads: per-block LDS 4.0 -> 2.5 MB. R6's mistake was load-at-use.
// Converts merged to one launch (R6's conv_all, known-correct). Combine kept
// separate (known-good).

typedef __bf16 bf16_t;
typedef __bf16 bf16x8 __attribute__((ext_vector_type(8)));
typedef float floatx4 __attribute__((ext_vector_type(4)));

#define THREADS 256
#define H4 4096

__device__ __forceinline__ void glds16(const void* g, void* l) {
  __builtin_amdgcn_global_load_lds((const __attribute__((address_space(1))) void*)g,
                                   (__attribute__((address_space(3))) void*)l,
                                   16, 0, 0);
}

// ============================ convert (single launch) ============================
__global__ __launch_bounds__(THREADS)
void conv_all(const float* __restrict__ x, const float* __restrict__ h,
              const float* __restrict__ Win, const float* __restrict__ Wst,
              const float* __restrict__ cpt, const float* __restrict__ Wci,
              const float* __restrict__ Wcs,
              bf16_t* __restrict__ xb, bf16_t* __restrict__ hb,
              bf16_t* __restrict__ Winb, bf16_t* __restrict__ Wstb,
              bf16_t* __restrict__ cb, bf16_t* __restrict__ Wcib,
              bf16_t* __restrict__ Wcsb)
{
  const int bid = blockIdx.x;
  if (bid < 5120) {
    const int c = bid * THREADS + threadIdx.x;
    const float* src; bf16_t* dst; int off;
    if      (c < 131072) { src = x;   dst = xb;   off = c; }
    else if (c < 262144) { src = h;   dst = hb;   off = c - 131072; }
    else if (c < 786432) { src = Win; dst = Winb; off = c - 262144; }
    else                 { src = Wst; dst = Wstb; off = c - 786432; }
    const size_t e0 = (size_t)off * 8;
    const float4 f0 = *(const float4*)(src + e0);
    const float4 f1 = *(const float4*)(src + e0 + 4);
    bf16x8 v;
    v[0] = (bf16_t)f0.x; v[1] = (bf16_t)f0.y; v[2] = (bf16_t)f0.z; v[3] = (bf16_t)f0.w;
    v[4] = (bf16_t)f1.x; v[5] = (bf16_t)f1.y; v[6] = (bf16_t)f1.z; v[7] = (bf16_t)f1.w;
    *(bf16x8*)(dst + e0) = v;
  } else {
    const int rid   = (bid - 5120) * 2 + (threadIdx.x >> 7);
    const int chunk = threadIdx.x & 127;
    const float* src; bf16_t* dst; int row;
    if      (rid < 1024) { src = cpt; dst = cb;   row = rid; }
    else if (rid < 5120) { src = Wci; dst = Wcib; row = rid - 1024; }
    else                 { src = Wcs; dst = Wcsb; row = rid - 5120; }
    bf16x8 v;
#pragma unroll
    for (int e = 0; e < 8; ++e) v[e] = (bf16_t)0.f;
    if (chunk < 125) {
      const size_t s0 = (size_t)row * 1000 + (size_t)chunk * 8;
      const float4 f0 = *(const float4*)(src + s0);
      const float4 f1 = *(const float4*)(src + s0 + 4);
      v[0] = (bf16_t)f0.x; v[1] = (bf16_t)f0.y; v[2] = (bf16_t)f0.z; v[3] = (bf16_t)f0.w;
      v[4] = (bf16_t)f1.x; v[5] = (bf16_t)f1.y; v[6] = (bf16_t)f1.z; v[7] = (bf16_t)f1.w;
    }
    *(bf16x8*)(dst + (size_t)row * 1024 + (size_t)chunk * 8) = v;
  }
}

// ============================ GEMM building blocks ============================
// W-tile staging: 64 rows x 128 B, XOR-swizzled chunks (R5 exact, known-good)
__device__ __forceinline__ void stage2(const bf16_t* __restrict__ g, int row0, int kByte,
                                       char* s, int w, int lane) {
#pragma unroll
  for (int it = 0; it < 2; ++it) {
    const int flat = it * 4096 + w * 1024 + lane * 16;
    const int row  = flat >> 7;
    const int slot = (flat >> 4) & 7;
    const int srcb = kByte + ((slot ^ (row & 7)) << 4);
    glds16((const char*)g + (size_t)(row0 + row) * 2048 + srcb, s + it * 4096 + w * 1024);
  }
}

// A-frag direct loads for one 128B K-iter: f[ks*2+mi] = A[row0+mi*16+l15][kb + ks*32 + quad*8 ..]
__device__ __forceinline__ void loadA4(const bf16_t* __restrict__ A, int row0,
                                       int l15, int quad, int kb, bf16x8 (&f)[4]) {
  const char* base = (const char*)A + (size_t)(row0 + l15) * 2048 + kb + quad * 16;
#pragma unroll
  for (int ks = 0; ks < 2; ++ks)
#pragma unroll
    for (int mi = 0; mi < 2; ++mi)
      f[ks * 2 + mi] = *(const bf16x8*)(base + (size_t)mi * 16 * 2048 + ks * 64);
}

__device__ __forceinline__ void computeB1(const char* sB, const bf16x8 (&a)[4],
                                          int l15, int quad, floatx4 (&acc)[2][4]) {
#pragma unroll
  for (int ks = 0; ks < 2; ++ks) {
    bf16x8 b[4];
#pragma unroll
    for (int ni = 0; ni < 4; ++ni) {
      const int r = ni * 16 + l15;
      const int c = (ks * 4 + quad) ^ (r & 7);
      b[ni] = *(const bf16x8*)(sB + r * 128 + c * 16);
    }
#pragma unroll
    for (int mi = 0; mi < 2; ++mi)
#pragma unroll
      for (int ni = 0; ni < 4; ++ni)
        acc[mi][ni] = __builtin_amdgcn_mfma_f32_16x16x32_bf16(a[ks * 2 + mi], b[ni],
                                                              acc[mi][ni], 0, 0, 0);
  }
}

// Phase: acc += A[M-tile] * W[N-tile]^T, K=1024, A in registers (+1 prefetch)
__device__ __forceinline__ void phase1B(const bf16_t* __restrict__ A,
                                        const bf16_t* __restrict__ W,
                                        int row0, int N0, char* sB,
                                        int w, int lane, int l15, int quad,
                                        floatx4 (&acc)[2][4]) {
  bf16x8 cur[4], nxt[4];
  loadA4(A, row0, l15, quad, 0, cur);
  for (int i = 0; i < 16; ++i) {
    const int kb = i * 128;
    __syncthreads();                       // prev compute done
    stage2(W, N0, kb, sB, w, lane);
    __syncthreads();                       // B visible (drains vmcnt incl. our prefetch)
    if (i < 15) loadA4(A, row0, l15, quad, kb + 128, nxt);  // +1-iter prefetch
    computeB1(sB, cur, l15, quad, acc);
    if (i < 15) {
#pragma unroll
      for (int j = 0; j < 4; ++j) cur[j] = nxt[j];
    }
  }
}

// Fused concept phase: one A (registers, prefetched) vs two W's
__device__ __forceinline__ void phase2B(const bf16_t* __restrict__ A,
                                        const bf16_t* __restrict__ W1,
                                        const bf16_t* __restrict__ W2,
                                        int row0, int N0, char* sB1, char* sB2,
                                        int w, int lane, int l15, int quad,
                                        floatx4 (&acc1)[2][4], floatx4 (&acc2)[2][4]) {
  bf16x8 cur[4], nxt[4];
  loadA4(A, row0, l15, quad, 0, cur);
  for (int i = 0; i < 16; ++i) {
    const int kb = i * 128;
    __syncthreads();
    stage2(W1, N0, kb, sB1, w, lane);
    stage2(W2, N0, kb, sB2, w, lane);
    __syncthreads();
    if (i < 15) loadA4(A, row0, l15, quad, kb + 128, nxt);
#pragma unroll
    for (int ks = 0; ks < 2; ++ks) {
      bf16x8 b1[4], b2[4];
#pragma unroll
      for (int ni = 0; ni < 4; ++ni) {
        const int r = ni * 16 + l15;
        const int c = (ks * 4 + quad) ^ (r & 7);
        b1[ni] = *(const bf16x8*)(sB1 + r * 128 + c * 16);
        b2[ni] = *(const bf16x8*)(sB2 + r * 128 + c * 16);
      }
#pragma unroll
      for (int mi = 0; mi < 2; ++mi)
#pragma unroll
        for (int ni = 0; ni < 4; ++ni) {
          acc1[mi][ni] = __builtin_amdgcn_mfma_f32_16x16x32_bf16(cur[ks * 2 + mi], b1[ni],
                                                                 acc1[mi][ni], 0, 0, 0);
          acc2[mi][ni] = __builtin_amdgcn_mfma_f32_16x16x32_bf16(cur[ks * 2 + mi], b2[ni],
                                                                 acc2[mi][ni], 0, 0, 0);
        }
    }
    if (i < 15) {
#pragma unroll
      for (int j = 0; j < 4; ++j) cur[j] = nxt[j];
    }
  }
}

__global__ __launch_bounds__(THREADS)
void scn_gemm_fast2(const bf16_t* __restrict__ xb,   const bf16_t* __restrict__ hb,
                    const bf16_t* __restrict__ cb,
                    const bf16_t* __restrict__ Winb, const bf16_t* __restrict__ Wstb,
                    const bf16_t* __restrict__ Wcib, const bf16_t* __restrict__ Wcsb,
                    bf16_t* __restrict__ hidden)
{
  __shared__ __align__(16) char sB1[64 * 128];  // 8 KiB
  __shared__ __align__(16) char sB2[64 * 128];  // 8 KiB
  const int tid = threadIdx.x;
  const int w = tid >> 6, lane = tid & 63, l15 = lane & 15, quad = lane >> 4;
  const int N0 = blockIdx.x * 64, M0 = blockIdx.y * 128;
  const int row0 = M0 + w * 32;

  floatx4 acc0[2][4], acc1[2][4], acc2[2][4];
  const floatx4 z = {0.f, 0.f, 0.f, 0.f};
#pragma unroll
  for (int mi = 0; mi < 2; ++mi)
#pragma unroll
    for (int ni = 0; ni < 4; ++ni) { acc0[mi][ni] = z; acc1[mi][ni] = z; acc2[mi][ni] = z; }

  // xi = x @ Win^T
  phase1B(xb, Winb, row0, N0, sB1, w, lane, l15, quad, acc0);
  // gi = concept @ Wci^T ; gs = concept @ Wcs^T (A staged once in regs)
  phase2B(cb, Wcib, Wcsb, row0, N0, sB1, sB2, w, lane, l15, quad, acc1, acc2);
  // P = xi * gi (same C/D layout); recycle acc1 for hs
#pragma unroll
  for (int mi = 0; mi < 2; ++mi)
#pragma unroll
    for (int ni = 0; ni < 4; ++ni) { acc0[mi][ni] = acc0[mi][ni] * acc1[mi][ni]; acc1[mi][ni] = z; }
  // hs = h @ Wst^T
  phase1B(hb, Wstb, row0, N0, sB1, w, lane, l15, quad, acc1);

  // hidden = sigmoid(P + hs*gs); C/D layout: row = quad*4 + r, col = l15
#pragma unroll
  for (int mi = 0; mi < 2; ++mi)
#pragma unroll
    for (int ni = 0; ni < 4; ++ni)
#pragma unroll
      for (int r = 0; r < 4; ++r) {
        const float e = acc0[mi][ni][r] + acc1[mi][ni][r] * acc2[mi][ni][r];
        const float s = 1.f / (1.f + __expf(-e));
        const int row = row0 + mi * 16 + quad * 4 + r;
        const int col = N0 + ni * 16 + l15;
        hidden[(size_t)row * H4 + col] = (bf16_t)s;
      }
}

// ============================ combine (R5 exact) ============================
__global__ __launch_bounds__(THREADS)
void scn_combine(const bf16_t* __restrict__ hidden, const float* __restrict__ cs,
                 float* __restrict__ out)
{
  const int t = blockIdx.x * THREADS + threadIdx.x;
  const size_t idx = (size_t)t * 8;
  const size_t b = idx >> 10, col = idx & 1023;
  const size_t hb = b * H4 + col;
  const bf16x8 vi = *(const bf16x8*)(hidden + hb);
  const bf16x8 vf = *(const bf16x8*)(hidden + hb + 1024);
  const bf16x8 vo = *(const bf16x8*)(hidden + hb + 2048);
  const bf16x8 vc = *(const bf16x8*)(hidden + hb + 3072);
  const float4 a = *(const float4*)(cs + idx);
  const float4 d = *(const float4*)(cs + idx + 4);
  const float cv[8] = {a.x, a.y, a.z, a.w, d.x, d.y, d.z, d.w};
  float ht[8], ct[8];
#pragma unroll
  for (int e = 0; e < 8; ++e) {
    ct[e] = (float)vi[e] * (float)vc[e] + (float)vf[e] * cv[e];
    ht[e] = (float)vo[e] * tanhf(ct[e]);
  }
  *(float4*)(out + idx)     = make_float4(ht[0], ht[1], ht[2], ht[3]);
  *(float4*)(out + idx + 4) = make_float4(ht[4], ht[5], ht[6], ht[7]);
  float* outc = out + (1u << 20);
  *(float4*)(outc + idx)     = make_float4(ct[0], ct[1], ct[2], ct[3]);
  *(float4*)(outc + idx + 4) = make_float4(ct[4], ct[5], ct[6], ct[7]);
}

// ============================ legacy fallback (R4, known-good) ============================
__device__ __forceinline__ void compute_block_l(const char* sA, const char* sB,
                                                int w, int l15, int quad,
                                                floatx4 (&acc)[2][4]) {
#pragma unroll
  for (int ks = 0; ks < 2; ++ks) {
    bf16x8 af[2], bfr[4];
#pragma unroll
    for (int mi = 0; mi < 2; ++mi) {
      const int r = w * 32 + mi * 16 + l15;
      const int c = (ks * 4 + quad) ^ (r & 7);
      af[mi] = *(const bf16x8*)(sA + r * 128 + c * 16);
    }
#pragma unroll
    for (int ni = 0; ni < 4; ++ni) {
      const int r = ni * 16 + l15;
      const int c = (ks * 4 + quad) ^ (r & 7);
      bfr[ni] = *(const bf16x8*)(sB + r * 128 + c * 16);
    }
#pragma unroll
    for (int mi = 0; mi < 2; ++mi)
#pragma unroll
      for (int ni = 0; ni < 4; ++ni)
        acc[mi][ni] = __builtin_amdgcn_mfma_f32_16x16x32_bf16(af[mi], bfr[ni], acc[mi][ni], 0, 0, 0);
  }
}

template<int ITERS>
__device__ __forceinline__ void stage_tile_f32(const char* __restrict__ g, int row0,
                                               int Kelems, int kBase, char* s, int tid)
{
#pragma unroll
  for (int it = 0; it < ITERS; ++it) {
    const int flat = it * 4096 + tid * 16;
    const int row  = flat >> 7;
    const int slot = (flat >> 4) & 7;
    const int eb   = kBase + ((slot ^ (row & 7)) << 3);
    bf16x8 v;
#pragma unroll
    for (int e = 0; e < 8; ++e) v[e] = (bf16_t)0.f;
    if (eb + 8 <= Kelems) {
      const size_t e0 = (size_t)(row0 + row) * (size_t)Kelems + (size_t)eb;
      const float4 f0 = *(const float4*)(g + e0 * 4);
      const float4 f1 = *(const float4*)(g + e0 * 4 + 16);
      v[0] = (bf16_t)f0.x; v[1] = (bf16_t)f0.y; v[2] = (bf16_t)f0.z; v[3] = (bf16_t)f0.w;
      v[4] = (bf16_t)f1.x; v[5] = (bf16_t)f1.y; v[6] = (bf16_t)f1.z; v[7] = (bf16_t)f1.w;
    }
    *(bf16x8*)(s + flat) = v;
  }
}

__device__ __forceinline__ void gemm_phase_legacy(
    const char* __restrict__ gA, int M0, const char* __restrict__ gW, int N0,
    int Kelems, char* sA, char* sB, int tid, floatx4 (&acc)[2][4])
{
  const int w = tid >> 6, lane = tid & 63, l15 = lane & 15, quad = lane >> 4;
  const int iters = (Kelems + 63) >> 6;
  for (int i = 0; i < iters; ++i) {
    const int kb = i * 64;
    __syncthreads();
    stage_tile_f32<4>(gA, M0, Kelems, kb, sA, tid);
    stage_tile_f32<2>(gW, N0, Kelems, kb, sB, tid);
    __syncthreads();
    compute_block_l(sA, sB, w, l15, quad, acc);
  }
}

__global__ __launch_bounds__(THREADS)
void scn_gemm_legacy(const char* __restrict__ x, const char* __restrict__ h,
                     const char* __restrict__ cpt,
                     const char* __restrict__ Win, const char* __restrict__ Wst,
                     const char* __restrict__ Wci, const char* __restrict__ Wcs,
                     bf16_t* __restrict__ hidden)
{
  __shared__ __align__(16) char sA[128 * 128];
  __shared__ __align__(16) char sB[64 * 128];
  const int tid = threadIdx.x;
  const int N0 = blockIdx.x * 64, M0 = blockIdx.y * 128;
  floatx4 acc0[2][4], acc1[2][4], acc2[2][4];
  const floatx4 z = {0.f, 0.f, 0.f, 0.f};
#pragma unroll
  for (int mi = 0; mi < 2; ++mi)
#pragma unroll
    for (int ni = 0; ni < 4; ++ni) { acc0[mi][ni] = z; acc1[mi][ni] = z; acc2[mi][ni] = z; }
  gemm_phase_legacy(x, M0, Win, N0, 1024, sA, sB, tid, acc0);
  gemm_phase_legacy(cpt, M0, Wci, N0, 1000, sA, sB, tid, acc1);
#pragma unroll
  for (int mi = 0; mi < 2; ++mi)
#pragma unroll
    for (int ni = 0; ni < 4; ++ni) { acc0[mi][ni] = acc0[mi][ni] * acc1[mi][ni]; acc1[mi][ni] = z; }
  gemm_phase_legacy(h, M0, Wst, N0, 1024, sA, sB, tid, acc1);
  gemm_phase_legacy(cpt, M0, Wcs, N0, 1000, sA, sB, tid, acc2);
  const int w = tid >> 6, lane = tid & 63, l15 = lane & 15, quad = lane >> 4;
#pragma unroll
  for (int mi = 0; mi < 2; ++mi)
#pragma unroll
    for (int ni = 0; ni < 4; ++ni)
#pragma unroll
      for (int r = 0; r < 4; ++r) {
        const float e = acc0[mi][ni][r] + acc1[mi][ni][r] * acc2[mi][ni][r];
        const float s = 1.f / (1.f + __expf(-e));
        const int row = M0 + w * 32 + mi * 16 + quad * 4 + r;
        const int col = N0 + ni * 16 + l15;
        hidden[(size_t)row * H4 + col] = (bf16_t)s;
      }
}

extern "C" void kernel_launch(void* const* d_in, const int* in_sizes, int n_in,
                              void* d_out, int out_size, void* d_ws, size_t ws_size,
                              hipStream_t stream) {
  (void)in_sizes; (void)n_in; (void)out_size;
  const float* x   = (const float*)d_in[0];
  const float* h   = (const float*)d_in[1];
  const float* cst = (const float*)d_in[2];
  const float* cpt = (const float*)d_in[3];
  const float* Win = (const float*)d_in[4];
  const float* Wst = (const float*)d_in[5];
  const float* Wci = (const float*)d_in[6];
  const float* Wcs = (const float*)d_in[7];
  float* out = (float*)d_out;
  const size_t MB = 1u << 20;

  if (ws_size >= 46 * MB) {
    char* ws = (char*)d_ws;
    bf16_t* xb    = (bf16_t*)(ws);            // 2 MiB
    bf16_t* hbuf  = (bf16_t*)(ws + 2 * MB);   // 2 MiB
    bf16_t* cb    = (bf16_t*)(ws + 4 * MB);   // 2 MiB (K padded)
    bf16_t* Winb  = (bf16_t*)(ws + 6 * MB);   // 8 MiB
    bf16_t* Wstb  = (bf16_t*)(ws + 14 * MB);  // 8 MiB
    bf16_t* Wcib  = (bf16_t*)(ws + 22 * MB);  // 8 MiB (K padded)
    bf16_t* Wcsb  = (bf16_t*)(ws + 30 * MB);  // 8 MiB (K padded)
    bf16_t* hidden= (bf16_t*)(ws + 38 * MB);  // 8 MiB
    conv_all<<<5120 + 4608, THREADS, 0, stream>>>(x, h, Win, Wst, cpt, Wci, Wcs,
                                                  xb, hbuf, Winb, Wstb, cb, Wcib, Wcsb);
    dim3 grid(H4 / 64, 1024 / 128);           // 64 x 8 = 512 blocks
    scn_gemm_fast2<<<grid, THREADS, 0, stream>>>(xb, hbuf, cb, Winb, Wstb, Wcib, Wcsb, hidden);
    scn_combine<<<(1024 * 1024 / 8) / THREADS, THREADS, 0, stream>>>(hidden, cst, out);
  } else {
    bf16_t* hidden = (bf16_t*)((char*)d_ws + 256);
    dim3 grid(H4 / 64, 1024 / 128);
    scn_gemm_legacy<<<grid, THREADS, 0, stream>>>(
        (const char*)x, (const char*)h, (const char*)cpt,
        (const char*)Win, (const char*)Wst, (const char*)Wci, (const char*)Wcs, hidden);
    scn_combine<<<(1024 * 1024 / 8) / THREADS, THREADS, 0, stream>>>(hidden, cst, out);
  }
}

// Round 8
// 189.254 us; speedup vs baseline: 1.2565x; 1.2565x over previous
//
#include <hip/hip_runtime.h>
#include <math.h>

// SCNCore: hidden = sigmoid((concept@Wci^T)*(x@Win^T) + (concept@Wcs^T)*(h@Wst^T))
//          i,f,o,cc = split(hidden,4); c_t = i*cc + f*c_state; h_t = o*tanh(c_t)
// B=1024, IN=H=1024, C=1000, 4H=4096. Inputs fp32, outputs fp32.
//
// R8: A-operands in FRAGMENT-MAJOR global layout (written by convert kernel):
//   chunk q=((g*128+c)*16+l15) holds A[g*16+l15][c*8..c*8+7]  -> wave A-frag
//   load = 1KB fully coalesced (R6/R7 failed on stride-2048 scatter).
// LDS carries only W tiles (glds16 + XOR swizzle, R5-proven), double-buffered
// -> ONE barrier per K-iter. Gate-interleaved N (R6-proven) fuses the LSTM
// epilogue; no hidden buffer, no combine kernel. Two paired passes keep
// <=3 acc sets (~220 VGPR).

typedef __bf16 bf16_t;
typedef __bf16 bf16x8 __attribute__((ext_vector_type(8)));
typedef float floatx4 __attribute__((ext_vector_type(4)));

#define THREADS 256

__device__ __forceinline__ void glds16(const void* g, void* l) {
  __builtin_amdgcn_global_load_lds((const __attribute__((address_space(1))) void*)g,
                                   (__attribute__((address_space(3))) void*)l,
                                   16, 0, 0);
}

// ============================ convert (single launch, 9728 blocks) ============================
// blocks [0,4096): Win/Wst row-major bf16
// blocks [4096,8192): Wci/Wcs row-major bf16, K padded 1000->1024 (zeros)
// blocks [8192,9728): x / h / concept -> FRAGMENT-MAJOR bf16 (concept K-padded)
__global__ __launch_bounds__(THREADS)
void conv_all(const float* __restrict__ x, const float* __restrict__ h,
              const float* __restrict__ cpt,
              const float* __restrict__ Win, const float* __restrict__ Wst,
              const float* __restrict__ Wci, const float* __restrict__ Wcs,
              bf16_t* __restrict__ xF, bf16_t* __restrict__ hF, bf16_t* __restrict__ cF,
              bf16_t* __restrict__ Winb, bf16_t* __restrict__ Wstb,
              bf16_t* __restrict__ Wcib, bf16_t* __restrict__ Wcsb)
{
  const int bid = blockIdx.x;
  if (bid < 4096) {
    const int cix = bid * THREADS + threadIdx.x;    // 0..1048575 chunks of 8
    const float* src; bf16_t* dst; int off;
    if (cix < 524288) { src = Win; dst = Winb; off = cix; }
    else              { src = Wst; dst = Wstb; off = cix - 524288; }
    const size_t e0 = (size_t)off * 8;
    const float4 f0 = *(const float4*)(src + e0);
    const float4 f1 = *(const float4*)(src + e0 + 4);
    bf16x8 v;
    v[0] = (bf16_t)f0.x; v[1] = (bf16_t)f0.y; v[2] = (bf16_t)f0.z; v[3] = (bf16_t)f0.w;
    v[4] = (bf16_t)f1.x; v[5] = (bf16_t)f1.y; v[6] = (bf16_t)f1.z; v[7] = (bf16_t)f1.w;
    *(bf16x8*)(dst + e0) = v;
  } else if (bid < 8192) {
    const int rid   = (bid - 4096) * 2 + (threadIdx.x >> 7);  // 0..8191
    const int chunk = threadIdx.x & 127;
    const float* src; bf16_t* dst; int row;
    if (rid < 4096) { src = Wci; dst = Wcib; row = rid; }
    else            { src = Wcs; dst = Wcsb; row = rid - 4096; }
    bf16x8 v;
#pragma unroll
    for (int e = 0; e < 8; ++e) v[e] = (bf16_t)0.f;
    if (chunk < 125) {
      const size_t s0 = (size_t)row * 1000 + (size_t)chunk * 8;
      const float4 f0 = *(const float4*)(src + s0);
      const float4 f1 = *(const float4*)(src + s0 + 4);
      v[0] = (bf16_t)f0.x; v[1] = (bf16_t)f0.y; v[2] = (bf16_t)f0.z; v[3] = (bf16_t)f0.w;
      v[4] = (bf16_t)f1.x; v[5] = (bf16_t)f1.y; v[6] = (bf16_t)f1.z; v[7] = (bf16_t)f1.w;
    }
    *(bf16x8*)(dst + (size_t)row * 1024 + (size_t)chunk * 8) = v;
  } else {
    // fragment-major activations: q = ((g*128 + c)*16 + l15), holds
    // A[g*16+l15][c*8 .. c*8+7]; writes fully coalesced (dst = q*8 elems)
    const int fb = bid - 8192;                      // 0..1535
    const int q  = (fb & 511) * THREADS + threadIdx.x;  // 0..131071
    const int l15 = q & 15, c = (q >> 4) & 127, g = q >> 11;
    const int row = g * 16 + l15;
    bf16x8 v;
#pragma unroll
    for (int e = 0; e < 8; ++e) v[e] = (bf16_t)0.f;
    const float* src; bf16_t* dst; int K; int valid;
    if      (fb < 512)  { src = x;   dst = xF; K = 1024; valid = 1; }
    else if (fb < 1024) { src = h;   dst = hF; K = 1024; valid = 1; }
    else                { src = cpt; dst = cF; K = 1000; valid = (c < 125); }
    if (valid) {
      const size_t s0 = (size_t)row * K + (size_t)c * 8;
      const float4 f0 = *(const float4*)(src + s0);
      const float4 f1 = *(const float4*)(src + s0 + 4);
      v[0] = (bf16_t)f0.x; v[1] = (bf16_t)f0.y; v[2] = (bf16_t)f0.z; v[3] = (bf16_t)f0.w;
      v[4] = (bf16_t)f1.x; v[5] = (bf16_t)f1.y; v[6] = (bf16_t)f1.z; v[7] = (bf16_t)f1.w;
    }
    *(bf16x8*)(dst + (size_t)q * 8) = v;
  }
}

// ===================== fused dual-GEMM pass + LSTM epilogue =====================
// W-tile: 64 rows x 128 B, gate-interleaved: tile row r holds W row
// N0 + (r&15) + (r>>4)*1024 (R6-proven). XOR-swizzled chunks (R5-proven).
__device__ __forceinline__ void stageWg(const bf16_t* __restrict__ W, int N0, int kByte,
                                        char* s, int w, int lane) {
#pragma unroll
  for (int it = 0; it < 2; ++it) {
    const int flat = it * 4096 + w * 1024 + lane * 16;
    const int row  = flat >> 7;
    const int slot = (flat >> 4) & 7;
    const int srcb = kByte + ((slot ^ (row & 7)) << 4);
    const int wrow = N0 + (row & 15) + ((row >> 4) << 10);
    glds16((const char*)W + (size_t)wrow * 2048 + srcb, s + it * 4096 + w * 1024);
  }
}

// Coalesced A-frag loads from fragment-major buffers (2 A's, one K-iter).
__device__ __forceinline__ void loadFrags(const bf16_t* __restrict__ A1,
                                          const bf16_t* __restrict__ A2,
                                          int gBase, int iter, int quad, int l15,
                                          bf16x8 (&f)[2][4]) {
#pragma unroll
  for (int ks = 0; ks < 2; ++ks) {
    const int c = iter * 8 + ks * 4 + quad;
#pragma unroll
    for (int mi = 0; mi < 2; ++mi) {
      const size_t q = ((((size_t)(gBase + mi)) << 7) + c) * 16 + l15;
      f[0][ks * 2 + mi] = *(const bf16x8*)(A1 + q * 8);
      f[1][ks * 2 + mi] = *(const bf16x8*)(A2 + q * 8);
    }
  }
}

__device__ __forceinline__ void computeIter(const char* sW0, const char* sW1,
                                            const bf16x8 (&f)[2][4], int l15, int quad,
                                            floatx4 (&acc0)[2][4], floatx4 (&acc1)[2][4]) {
#pragma unroll
  for (int ks = 0; ks < 2; ++ks) {
#pragma unroll
    for (int ni = 0; ni < 4; ++ni) {
      const int r = ni * 16 + l15;
      const int c = (ks * 4 + quad) ^ (r & 7);
      const bf16x8 b0 = *(const bf16x8*)(sW0 + r * 128 + c * 16);
      const bf16x8 b1 = *(const bf16x8*)(sW1 + r * 128 + c * 16);
#pragma unroll
      for (int mi = 0; mi < 2; ++mi) {
        acc0[mi][ni] = __builtin_amdgcn_mfma_f32_16x16x32_bf16(f[0][ks * 2 + mi], b0,
                                                               acc0[mi][ni], 0, 0, 0);
        acc1[mi][ni] = __builtin_amdgcn_mfma_f32_16x16x32_bf16(f[1][ks * 2 + mi], b1,
                                                               acc1[mi][ni], 0, 0, 0);
      }
    }
  }
}

// One pass = two GEMMs sharing the K-loop: acc1 += A1*W1^T, acc2 += A2*W2^T.
// W double-buffered (1 barrier/iter); A frags prefetched +1 iter.
__device__ __forceinline__ void runPass(const bf16_t* __restrict__ A1,
                                        const bf16_t* __restrict__ A2,
                                        const bf16_t* __restrict__ W1,
                                        const bf16_t* __restrict__ W2,
                                        int gBase, int N0, char (*sW)[2][8192],
                                        int w, int lane, int l15, int quad,
                                        floatx4 (&acc1)[2][4], floatx4 (&acc2)[2][4]) {
  bf16x8 f[2][2][4];   // [buf][gemm][frag]
  stageWg(W1, N0, 0, sW[0][0], w, lane);
  stageWg(W2, N0, 0, sW[0][1], w, lane);
  loadFrags(A1, A2, gBase, 0, quad, l15, f[0]);
#pragma unroll 1
  for (int ii = 0; ii < 8; ++ii) {
    __syncthreads();                               // buf0(iter 2ii) staged & prior reads done
    {
      const int i = 2 * ii;
      stageWg(W1, N0, (i + 1) * 128, sW[1][0], w, lane);
      stageWg(W2, N0, (i + 1) * 128, sW[1][1], w, lane);
      loadFrags(A1, A2, gBase, i + 1, quad, l15, f[1]);
      computeIter(sW[0][0], sW[0][1], f[0], l15, quad, acc1, acc2);
    }
    __syncthreads();                               // buf1(iter 2ii+1) staged
    {
      if (ii < 7) {
        const int i = 2 * ii + 1;
        stageWg(W1, N0, (i + 1) * 128, sW[0][0], w, lane);
        stageWg(W2, N0, (i + 1) * 128, sW[0][1], w, lane);
        loadFrags(A1, A2, gBase, i + 1, quad, l15, f[0]);
      }
      computeIter(sW[1][0], sW[1][1], f[1], l15, quad, acc1, acc2);
    }
  }
}

__global__ __launch_bounds__(THREADS)
void scn_fused2(const bf16_t* __restrict__ xF, const bf16_t* __restrict__ hF,
                const bf16_t* __restrict__ cF,
                const bf16_t* __restrict__ Winb, const bf16_t* __restrict__ Wstb,
                const bf16_t* __restrict__ Wcib, const bf16_t* __restrict__ Wcsb,
                const float* __restrict__ cs, float* __restrict__ out)
{
  __shared__ __align__(16) char sW[2][2][8192];   // 32 KiB: [buf][which W]
  const int tid = threadIdx.x;
  const int w = tid >> 6, lane = tid & 63, l15 = lane & 15, quad = lane >> 4;
  const int N0 = blockIdx.x * 16;     // 16 cols per gate; grid.x = 64
  const int M0 = blockIdx.y * 128;    // grid.y = 8
  const int gBase = (M0 >> 4) + w * 2;

  floatx4 P[2][4], accA[2][4], accB[2][4];
  const floatx4 z = {0.f, 0.f, 0.f, 0.f};
#pragma unroll
  for (int mi = 0; mi < 2; ++mi)
#pragma unroll
    for (int ni = 0; ni < 4; ++ni) { accA[mi][ni] = z; accB[mi][ni] = z; }

  // pass 1: xi = x@Win^T (accA), gi = concept@Wci^T (accB)
  runPass(xF, cF, Winb, Wcib, gBase, N0, sW, w, lane, l15, quad, accA, accB);
#pragma unroll
  for (int mi = 0; mi < 2; ++mi)
#pragma unroll
    for (int ni = 0; ni < 4; ++ni) {
      P[mi][ni] = accA[mi][ni] * accB[mi][ni];
      accA[mi][ni] = z; accB[mi][ni] = z;
    }
  // pass 2: hs = h@Wst^T (accA), gs = concept@Wcs^T (accB)
  runPass(hF, cF, Wstb, Wcsb, gBase, N0, sW, w, lane, l15, quad, accA, accB);

  // epilogue (R6-proven): C/D row = quad*4+r, col = l15; ni = gate {i,f,o,cc}
#pragma unroll
  for (int mi = 0; mi < 2; ++mi)
#pragma unroll
    for (int r = 0; r < 4; ++r) {
      float g[4];
#pragma unroll
      for (int ni = 0; ni < 4; ++ni) {
        const float e = P[mi][ni][r] + accB[mi][ni][r] * accA[mi][ni][r];
        g[ni] = 1.f / (1.f + __expf(-e));
      }
      const int row = M0 + w * 32 + mi * 16 + quad * 4 + r;
      const int col = N0 + l15;
      const float cst = cs[(size_t)row * 1024 + col];
      const float ct = g[0] * g[3] + g[1] * cst;
      const float ht = g[2] * tanhf(ct);
      out[(size_t)row * 1024 + col] = ht;
      out[(size_t)(1u << 20) + (size_t)row * 1024 + col] = ct;
    }
}

// ============================ legacy fallback (R4, known-good) ============================
__device__ __forceinline__ void compute_block_l(const char* sA, const char* sB,
                                                int w, int l15, int quad,
                                                floatx4 (&acc)[2][4]) {
#pragma unroll
  for (int ks = 0; ks < 2; ++ks) {
    bf16x8 af[2], bfr[4];
#pragma unroll
    for (int mi = 0; mi < 2; ++mi) {
      const int r = w * 32 + mi * 16 + l15;
      const int c = (ks * 4 + quad) ^ (r & 7);
      af[mi] = *(const bf16x8*)(sA + r * 128 + c * 16);
    }
#pragma unroll
    for (int ni = 0; ni < 4; ++ni) {
      const int r = ni * 16 + l15;
      const int c = (ks * 4 + quad) ^ (r & 7);
      bfr[ni] = *(const bf16x8*)(sB + r * 128 + c * 16);
    }
#pragma unroll
    for (int mi = 0; mi < 2; ++mi)
#pragma unroll
      for (int ni = 0; ni < 4; ++ni)
        acc[mi][ni] = __builtin_amdgcn_mfma_f32_16x16x32_bf16(af[mi], bfr[ni], acc[mi][ni], 0, 0, 0);
  }
}

template<int ITERS>
__device__ __forceinline__ void stage_tile_f32(const char* __restrict__ g, int row0,
                                               int Kelems, int kBase, char* s, int tid)
{
#pragma unroll
  for (int it = 0; it < ITERS; ++it) {
    const int flat = it * 4096 + tid * 16;
    const int row  = flat >> 7;
    const int slot = (flat >> 4) & 7;
    const int eb   = kBase + ((slot ^ (row & 7)) << 3);
    bf16x8 v;
#pragma unroll
    for (int e = 0; e < 8; ++e) v[e] = (bf16_t)0.f;
    if (eb + 8 <= Kelems) {
      const size_t e0 = (size_t)(row0 + row) * (size_t)Kelems + (size_t)eb;
      const float4 f0 = *(const float4*)(g + e0 * 4);
      const float4 f1 = *(const float4*)(g + e0 * 4 + 16);
      v[0] = (bf16_t)f0.x; v[1] = (bf16_t)f0.y; v[2] = (bf16_t)f0.z; v[3] = (bf16_t)f0.w;
      v[4] = (bf16_t)f1.x; v[5] = (bf16_t)f1.y; v[6] = (bf16_t)f1.z; v[7] = (bf16_t)f1.w;
    }
    *(bf16x8*)(s + flat) = v;
  }
}

__device__ __forceinline__ void gemm_phase_legacy(
    const char* __restrict__ gA, int M0, const char* __restrict__ gW, int N0,
    int Kelems, char* sA, char* sB, int tid, floatx4 (&acc)[2][4])
{
  const int w = tid >> 6, lane = tid & 63, l15 = lane & 15, quad = lane >> 4;
  const int iters = (Kelems + 63) >> 6;
  for (int i = 0; i < iters; ++i) {
    const int kb = i * 64;
    __syncthreads();
    stage_tile_f32<4>(gA, M0, Kelems, kb, sA, tid);
    stage_tile_f32<2>(gW, N0, Kelems, kb, sB, tid);
    __syncthreads();
    compute_block_l(sA, sB, w, l15, quad, acc);
  }
}

__global__ __launch_bounds__(THREADS)
void scn_gemm_legacy(const char* __restrict__ x, const char* __restrict__ h,
                     const char* __restrict__ cpt,
                     const char* __restrict__ Win, const char* __restrict__ Wst,
                     const char* __restrict__ Wci, const char* __restrict__ Wcs,
                     bf16_t* __restrict__ hidden)
{
  __shared__ __align__(16) char sA[128 * 128];
  __shared__ __align__(16) char sB[64 * 128];
  const int tid = threadIdx.x;
  const int N0 = blockIdx.x * 64, M0 = blockIdx.y * 128;
  floatx4 acc0[2][4], acc1[2][4], acc2[2][4];
  const floatx4 z = {0.f, 0.f, 0.f, 0.f};
#pragma unroll
  for (int mi = 0; mi < 2; ++mi)
#pragma unroll
    for (int ni = 0; ni < 4; ++ni) { acc0[mi][ni] = z; acc1[mi][ni] = z; acc2[mi][ni] = z; }
  gemm_phase_legacy(x, M0, Win, N0, 1024, sA, sB, tid, acc0);
  gemm_phase_legacy(cpt, M0, Wci, N0, 1000, sA, sB, tid, acc1);
#pragma unroll
  for (int mi = 0; mi < 2; ++mi)
#pragma unroll
    for (int ni = 0; ni < 4; ++ni) { acc0[mi][ni] = acc0[mi][ni] * acc1[mi][ni]; acc1[mi][ni] = z; }
  gemm_phase_legacy(h, M0, Wst, N0, 1024, sA, sB, tid, acc1);
  gemm_phase_legacy(cpt, M0, Wcs, N0, 1000, sA, sB, tid, acc2);
  const int w = tid >> 6, lane = tid & 63, l15 = lane & 15, quad = lane >> 4;
#pragma unroll
  for (int mi = 0; mi < 2; ++mi)
#pragma unroll
    for (int ni = 0; ni < 4; ++ni)
#pragma unroll
      for (int r = 0; r < 4; ++r) {
        const float e = acc0[mi][ni][r] + acc1[mi][ni][r] * acc2[mi][ni][r];
        const float s = 1.f / (1.f + __expf(-e));
        const int row = M0 + w * 32 + mi * 16 + quad * 4 + r;
        const int col = N0 + ni * 16 + l15;
        hidden[(size_t)row * 4096 + col] = (bf16_t)s;
      }
}

__global__ __launch_bounds__(THREADS)
void scn_combine(const bf16_t* __restrict__ hidden, const float* __restrict__ cs,
                 float* __restrict__ out)
{
  const int t = blockIdx.x * THREADS + threadIdx.x;
  const size_t idx = (size_t)t * 8;
  const size_t b = idx >> 10, col = idx & 1023;
  const size_t hb = b * 4096 + col;
  const bf16x8 vi = *(const bf16x8*)(hidden + hb);
  const bf16x8 vf = *(const bf16x8*)(hidden + hb + 1024);
  const bf16x8 vo = *(const bf16x8*)(hidden + hb + 2048);
  const bf16x8 vc = *(const bf16x8*)(hidden + hb + 3072);
  const float4 a = *(const float4*)(cs + idx);
  const float4 d = *(const float4*)(cs + idx + 4);
  const float cv[8] = {a.x, a.y, a.z, a.w, d.x, d.y, d.z, d.w};
  float ht[8], ct[8];
#pragma unroll
  for (int e = 0; e < 8; ++e) {
    ct[e] = (float)vi[e] * (float)vc[e] + (float)vf[e] * cv[e];
    ht[e] = (float)vo[e] * tanhf(ct[e]);
  }
  *(float4*)(out + idx)     = make_float4(ht[0], ht[1], ht[2], ht[3]);
  *(float4*)(out + idx + 4) = make_float4(ht[4], ht[5], ht[6], ht[7]);
  float* outc = out + (1u << 20);
  *(float4*)(outc + idx)     = make_float4(ct[0], ct[1], ct[2], ct[3]);
  *(float4*)(outc + idx + 4) = make_float4(ct[4], ct[5], ct[6], ct[7]);
}

extern "C" void kernel_launch(void* const* d_in, const int* in_sizes, int n_in,
                              void* d_out, int out_size, void* d_ws, size_t ws_size,
                              hipStream_t stream) {
  (void)in_sizes; (void)n_in; (void)out_size;
  const float* x   = (const float*)d_in[0];
  const float* h   = (const float*)d_in[1];
  const float* cst = (const float*)d_in[2];
  const float* cpt = (const float*)d_in[3];
  const float* Win = (const float*)d_in[4];
  const float* Wst = (const float*)d_in[5];
  const float* Wci = (const float*)d_in[6];
  const float* Wcs = (const float*)d_in[7];
  float* out = (float*)d_out;
  const size_t MB = 1u << 20;

  if (ws_size >= 38 * MB) {
    char* ws = (char*)d_ws;
    bf16_t* xF   = (bf16_t*)(ws);            // 2 MiB  (fragment-major)
    bf16_t* hF   = (bf16_t*)(ws + 2 * MB);   // 2 MiB  (fragment-major)
    bf16_t* cF   = (bf16_t*)(ws + 4 * MB);   // 2 MiB  (fragment-major, K padded)
    bf16_t* Winb = (bf16_t*)(ws + 6 * MB);   // 8 MiB
    bf16_t* Wstb = (bf16_t*)(ws + 14 * MB);  // 8 MiB
    bf16_t* Wcib = (bf16_t*)(ws + 22 * MB);  // 8 MiB (K padded)
    bf16_t* Wcsb = (bf16_t*)(ws + 30 * MB);  // 8 MiB (K padded)
    conv_all<<<9728, THREADS, 0, stream>>>(x, h, cpt, Win, Wst, Wci, Wcs,
                                           xF, hF, cF, Winb, Wstb, Wcib, Wcsb);
    dim3 grid(64, 8);   // 64 gate-col groups x 8 row tiles
    scn_fused2<<<grid, THREADS, 0, stream>>>(xF, hF, cF, Winb, Wstb, Wcib, Wcsb, cst, out);
  } else {
    bf16_t* hidden = (bf16_t*)((char*)d_ws + 256);
    dim3 grid(4096 / 64, 1024 / 128);
    scn_gemm_legacy<<<grid, THREADS, 0, stream>>>(
        (const char*)x, (const char*)h, (const char*)cpt,
        (const char*)Win, (const char*)Wst, (const char*)Wci, (const char*)Wcs, hidden);
    scn_combine<<<(1024 * 1024 / 8) / THREADS, THREADS, 0, stream>>>(hidden, cst, out);
  }
}

// Round 9
// 169.460 us; speedup vs baseline: 1.4033x; 1.1168x over previous
//
#include <hip/hip_runtime.h>
#include <math.h>

// SCNCore: hidden = sigmoid((concept@Wci^T)*(x@Win^T) + (concept@Wcs^T)*(h@Wst^T))
//          i,f,o,cc = split(hidden,4); c_t = i*cc + f*c_state; h_t = o*tanh(c_t)
// B=1024, IN=H=1024, C=1000, 4H=4096. Inputs fp32, outputs fp32.
//
// R9: R5's 48us GEMM structure VERBATIM (A via glds16 into LDS, single-buffer,
// 3 phases, dual-B concept pass) with exactly two changes:
//   (a) W tiles gate-interleaved (tile row r -> W row (r>>4)*1024+bx*16+(r&15),
//       R6-proven) so each block owns cols bx*16..+15 of ALL four gates;
//   (b) LSTM combine fused into the epilogue -> no hidden buffer, no combine
//       kernel, one less launch. 2 launches total (conv_all + scn_gemm_fast3).

typedef __bf16 bf16_t;
typedef __bf16 bf16x8 __attribute__((ext_vector_type(8)));
typedef float floatx4 __attribute__((ext_vector_type(4)));

#define THREADS 256

__device__ __forceinline__ void glds16(const void* g, void* l) {
  __builtin_amdgcn_global_load_lds((const __attribute__((address_space(1))) void*)g,
                                   (__attribute__((address_space(3))) void*)l,
                                   16, 0, 0);
}

// ============================ convert (R6 verbatim, single launch) ============================
__global__ __launch_bounds__(THREADS)
void conv_all(const float* __restrict__ x, const float* __restrict__ h,
              const float* __restrict__ Win, const float* __restrict__ Wst,
              const float* __restrict__ cpt, const float* __restrict__ Wci,
              const float* __restrict__ Wcs,
              bf16_t* __restrict__ xb, bf16_t* __restrict__ hb,
              bf16_t* __restrict__ Winb, bf16_t* __restrict__ Wstb,
              bf16_t* __restrict__ cb, bf16_t* __restrict__ Wcib,
              bf16_t* __restrict__ Wcsb)
{
  const int bid = blockIdx.x;
  if (bid < 5120) {
    const int c = bid * THREADS + threadIdx.x;
    const float* src; bf16_t* dst; int off;
    if      (c < 131072) { src = x;   dst = xb;   off = c; }
    else if (c < 262144) { src = h;   dst = hb;   off = c - 131072; }
    else if (c < 786432) { src = Win; dst = Winb; off = c - 262144; }
    else                 { src = Wst; dst = Wstb; off = c - 786432; }
    const size_t e0 = (size_t)off * 8;
    const float4 f0 = *(const float4*)(src + e0);
    const float4 f1 = *(const float4*)(src + e0 + 4);
    bf16x8 v;
    v[0] = (bf16_t)f0.x; v[1] = (bf16_t)f0.y; v[2] = (bf16_t)f0.z; v[3] = (bf16_t)f0.w;
    v[4] = (bf16_t)f1.x; v[5] = (bf16_t)f1.y; v[6] = (bf16_t)f1.z; v[7] = (bf16_t)f1.w;
    *(bf16x8*)(dst + e0) = v;
  } else {
    const int rid   = (bid - 5120) * 2 + (threadIdx.x >> 7);
    const int chunk = threadIdx.x & 127;
    const float* src; bf16_t* dst; int row;
    if      (rid < 1024) { src = cpt; dst = cb;   row = rid; }
    else if (rid < 5120) { src = Wci; dst = Wcib; row = rid - 1024; }
    else                 { src = Wcs; dst = Wcsb; row = rid - 5120; }
    bf16x8 v;
#pragma unroll
    for (int e = 0; e < 8; ++e) v[e] = (bf16_t)0.f;
    if (chunk < 125) {
      const size_t s0 = (size_t)row * 1000 + (size_t)chunk * 8;
      const float4 f0 = *(const float4*)(src + s0);
      const float4 f1 = *(const float4*)(src + s0 + 4);
      v[0] = (bf16_t)f0.x; v[1] = (bf16_t)f0.y; v[2] = (bf16_t)f0.z; v[3] = (bf16_t)f0.w;
      v[4] = (bf16_t)f1.x; v[5] = (bf16_t)f1.y; v[6] = (bf16_t)f1.z; v[7] = (bf16_t)f1.w;
    }
    *(bf16x8*)(dst + (size_t)row * 1024 + (size_t)chunk * 8) = v;
  }
}

// ============================ GEMM building blocks (R5 verbatim) ============================
// A tile: 128 rows x 128 B, XOR-swizzled chunks, contiguous rows M0..M0+127
__device__ __forceinline__ void stage4(const bf16_t* __restrict__ g, int row0, int kByte,
                                       char* s, int w, int lane) {
#pragma unroll
  for (int it = 0; it < 4; ++it) {
    const int flat = it * 4096 + w * 1024 + lane * 16;
    const int row  = flat >> 7;
    const int slot = (flat >> 4) & 7;
    const int srcb = kByte + ((slot ^ (row & 7)) << 4);
    glds16((const char*)g + (size_t)(row0 + row) * 2048 + srcb, s + it * 4096 + w * 1024);
  }
}

// W tile: 64 rows x 128 B, gate-interleaved rows (tile row r -> W row
// (r>>4)*1024 + bx*16 + (r&15)), XOR-swizzled chunks
__device__ __forceinline__ void stage2g(const bf16_t* __restrict__ g, int bx, int kByte,
                                        char* s, int w, int lane) {
#pragma unroll
  for (int it = 0; it < 2; ++it) {
    const int flat = it * 4096 + w * 1024 + lane * 16;
    const int row  = flat >> 7;
    const int slot = (flat >> 4) & 7;
    const int srcb = kByte + ((slot ^ (row & 7)) << 4);
    const int wrow = ((row >> 4) << 10) + (bx << 4) + (row & 15);
    glds16((const char*)g + (size_t)wrow * 2048 + srcb, s + it * 4096 + w * 1024);
  }
}

__device__ __forceinline__ void compute_block(const char* sA, const char* sB,
                                              int w, int l15, int quad,
                                              floatx4 (&acc)[2][4]) {
#pragma unroll
  for (int ks = 0; ks < 2; ++ks) {
    bf16x8 af[2], bfr[4];
#pragma unroll
    for (int mi = 0; mi < 2; ++mi) {
      const int r = w * 32 + mi * 16 + l15;
      const int c = (ks * 4 + quad) ^ (r & 7);
      af[mi] = *(const bf16x8*)(sA + r * 128 + c * 16);
    }
#pragma unroll
    for (int ni = 0; ni < 4; ++ni) {
      const int r = ni * 16 + l15;
      const int c = (ks * 4 + quad) ^ (r & 7);
      bfr[ni] = *(const bf16x8*)(sB + r * 128 + c * 16);
    }
#pragma unroll
    for (int mi = 0; mi < 2; ++mi)
#pragma unroll
      for (int ni = 0; ni < 4; ++ni)
        acc[mi][ni] = __builtin_amdgcn_mfma_f32_16x16x32_bf16(af[mi], bfr[ni],
                                                              acc[mi][ni], 0, 0, 0);
  }
}

__device__ __forceinline__ void compute_block2(const char* sA, const char* sB1,
                                               const char* sB2, int w, int l15, int quad,
                                               floatx4 (&acc1)[2][4], floatx4 (&acc2)[2][4]) {
#pragma unroll
  for (int ks = 0; ks < 2; ++ks) {
    bf16x8 af[2], b1[4], b2[4];
#pragma unroll
    for (int mi = 0; mi < 2; ++mi) {
      const int r = w * 32 + mi * 16 + l15;
      const int c = (ks * 4 + quad) ^ (r & 7);
      af[mi] = *(const bf16x8*)(sA + r * 128 + c * 16);
    }
#pragma unroll
    for (int ni = 0; ni < 4; ++ni) {
      const int r = ni * 16 + l15;
      const int c = (ks * 4 + quad) ^ (r & 7);
      b1[ni] = *(const bf16x8*)(sB1 + r * 128 + c * 16);
      b2[ni] = *(const bf16x8*)(sB2 + r * 128 + c * 16);
    }
#pragma unroll
    for (int mi = 0; mi < 2; ++mi)
#pragma unroll
      for (int ni = 0; ni < 4; ++ni) {
        acc1[mi][ni] = __builtin_amdgcn_mfma_f32_16x16x32_bf16(af[mi], b1[ni],
                                                               acc1[mi][ni], 0, 0, 0);
        acc2[mi][ni] = __builtin_amdgcn_mfma_f32_16x16x32_bf16(af[mi], b2[ni],
                                                               acc2[mi][ni], 0, 0, 0);
      }
  }
}

__global__ __launch_bounds__(THREADS)
void scn_gemm_fast3(const bf16_t* __restrict__ xb,   const bf16_t* __restrict__ hb,
                    const bf16_t* __restrict__ cb,
                    const bf16_t* __restrict__ Winb, const bf16_t* __restrict__ Wstb,
                    const bf16_t* __restrict__ Wcib, const bf16_t* __restrict__ Wcsb,
                    const float* __restrict__ cs, float* __restrict__ out)
{
  __shared__ __align__(16) char sA [128 * 128];  // 16 KiB
  __shared__ __align__(16) char sB1[ 64 * 128];  //  8 KiB
  __shared__ __align__(16) char sB2[ 64 * 128];  //  8 KiB
  const int tid = threadIdx.x;
  const int w = tid >> 6, lane = tid & 63, l15 = lane & 15, quad = lane >> 4;
  const int bx = blockIdx.x;           // 16 cols per gate; grid.x = 64
  const int M0 = blockIdx.y * 128;     // grid.y = 8
  const int row0 = M0 + w * 32;

  floatx4 acc0[2][4], acc1[2][4], acc2[2][4];
  const floatx4 z = {0.f, 0.f, 0.f, 0.f};
#pragma unroll
  for (int mi = 0; mi < 2; ++mi)
#pragma unroll
    for (int ni = 0; ni < 4; ++ni) { acc0[mi][ni] = z; acc1[mi][ni] = z; acc2[mi][ni] = z; }

  // phase 1: xi = x @ Win^T -> acc0
  for (int i = 0; i < 16; ++i) {
    const int kb = i * 128;
    __syncthreads();
    stage4(xb, M0, kb, sA, w, lane);
    stage2g(Winb, bx, kb, sB1, w, lane);
    __syncthreads();
    compute_block(sA, sB1, w, l15, quad, acc0);
  }
  // phase 2 (fused): gi -> acc1, gs -> acc2 (concept tile staged once)
  for (int i = 0; i < 16; ++i) {
    const int kb = i * 128;
    __syncthreads();
    stage4(cb, M0, kb, sA, w, lane);
    stage2g(Wcib, bx, kb, sB1, w, lane);
    stage2g(Wcsb, bx, kb, sB2, w, lane);
    __syncthreads();
    compute_block2(sA, sB1, sB2, w, l15, quad, acc1, acc2);
  }
  // P = xi * gi (same C/D fragment layout); recycle acc1 for hs
#pragma unroll
  for (int mi = 0; mi < 2; ++mi)
#pragma unroll
    for (int ni = 0; ni < 4; ++ni) { acc0[mi][ni] = acc0[mi][ni] * acc1[mi][ni]; acc1[mi][ni] = z; }
  // phase 3: hs = h @ Wst^T -> acc1
  for (int i = 0; i < 16; ++i) {
    const int kb = i * 128;
    __syncthreads();
    stage4(hb, M0, kb, sA, w, lane);
    stage2g(Wstb, bx, kb, sB1, w, lane);
    __syncthreads();
    compute_block(sA, sB1, w, l15, quad, acc1);
  }

  // fused LSTM epilogue: e = P + gs*hs; ni = gate {0:i,1:f,2:o,3:cc}
  // C/D layout: row = quad*4 + r, col = l15 (col-within-gate = bx*16 + l15)
#pragma unroll
  for (int mi = 0; mi < 2; ++mi)
#pragma unroll
    for (int r = 0; r < 4; ++r) {
      float g[4];
#pragma unroll
      for (int ni = 0; ni < 4; ++ni) {
        const float e = acc0[mi][ni][r] + acc2[mi][ni][r] * acc1[mi][ni][r];
        g[ni] = 1.f / (1.f + __expf(-e));
      }
      const int row = row0 + mi * 16 + quad * 4 + r;
      const int col = (bx << 4) + l15;
      const float cst = cs[(size_t)row * 1024 + col];
      const float ct = g[0] * g[3] + g[1] * cst;
      const float ht = g[2] * tanhf(ct);
      out[(size_t)row * 1024 + col] = ht;
      out[(size_t)(1u << 20) + (size_t)row * 1024 + col] = ct;
    }
}

// ============================ legacy fallback (R4, known-good) ============================
__device__ __forceinline__ void compute_block_l(const char* sA, const char* sB,
                                                int w, int l15, int quad,
                                                floatx4 (&acc)[2][4]) {
#pragma unroll
  for (int ks = 0; ks < 2; ++ks) {
    bf16x8 af[2], bfr[4];
#pragma unroll
    for (int mi = 0; mi < 2; ++mi) {
      const int r = w * 32 + mi * 16 + l15;
      const int c = (ks * 4 + quad) ^ (r & 7);
      af[mi] = *(const bf16x8*)(sA + r * 128 + c * 16);
    }
#pragma unroll
    for (int ni = 0; ni < 4; ++ni) {
      const int r = ni * 16 + l15;
      const int c = (ks * 4 + quad) ^ (r & 7);
      bfr[ni] = *(const bf16x8*)(sB + r * 128 + c * 16);
    }
#pragma unroll
    for (int mi = 0; mi < 2; ++mi)
#pragma unroll
      for (int ni = 0; ni < 4; ++ni)
        acc[mi][ni] = __builtin_amdgcn_mfma_f32_16x16x32_bf16(af[mi], bfr[ni], acc[mi][ni], 0, 0, 0);
  }
}

template<int ITERS>
__device__ __forceinline__ void stage_tile_f32(const char* __restrict__ g, int row0,
                                               int Kelems, int kBase, char* s, int tid)
{
#pragma unroll
  for (int it = 0; it < ITERS; ++it) {
    const int flat = it * 4096 + tid * 16;
    const int row  = flat >> 7;
    const int slot = (flat >> 4) & 7;
    const int eb   = kBase + ((slot ^ (row & 7)) << 3);
    bf16x8 v;
#pragma unroll
    for (int e = 0; e < 8; ++e) v[e] = (bf16_t)0.f;
    if (eb + 8 <= Kelems) {
      const size_t e0 = (size_t)(row0 + row) * (size_t)Kelems + (size_t)eb;
      const float4 f0 = *(const float4*)(g + e0 * 4);
      const float4 f1 = *(const float4*)(g + e0 * 4 + 16);
      v[0] = (bf16_t)f0.x; v[1] = (bf16_t)f0.y; v[2] = (bf16_t)f0.z; v[3] = (bf16_t)f0.w;
      v[4] = (bf16_t)f1.x; v[5] = (bf16_t)f1.y; v[6] = (bf16_t)f1.z; v[7] = (bf16_t)f1.w;
    }
    *(bf16x8*)(s + flat) = v;
  }
}

__device__ __forceinline__ void gemm_phase_legacy(
    const char* __restrict__ gA, int M0, const char* __restrict__ gW, int N0,
    int Kelems, char* sA, char* sB, int tid, floatx4 (&acc)[2][4])
{
  const int w = tid >> 6, lane = tid & 63, l15 = lane & 15, quad = lane >> 4;
  const int iters = (Kelems + 63) >> 6;
  for (int i = 0; i < iters; ++i) {
    const int kb = i * 64;
    __syncthreads();
    stage_tile_f32<4>(gA, M0, Kelems, kb, sA, tid);
    stage_tile_f32<2>(gW, N0, Kelems, kb, sB, tid);
    __syncthreads();
    compute_block_l(sA, sB, w, l15, quad, acc);
  }
}

__global__ __launch_bounds__(THREADS)
void scn_gemm_legacy(const char* __restrict__ x, const char* __restrict__ h,
                     const char* __restrict__ cpt,
                     const char* __restrict__ Win, const char* __restrict__ Wst,
                     const char* __restrict__ Wci, const char* __restrict__ Wcs,
                     bf16_t* __restrict__ hidden)
{
  __shared__ __align__(16) char sA[128 * 128];
  __shared__ __align__(16) char sB[64 * 128];
  const int tid = threadIdx.x;
  const int N0 = blockIdx.x * 64, M0 = blockIdx.y * 128;
  floatx4 acc0[2][4], acc1[2][4], acc2[2][4];
  const floatx4 z = {0.f, 0.f, 0.f, 0.f};
#pragma unroll
  for (int mi = 0; mi < 2; ++mi)
#pragma unroll
    for (int ni = 0; ni < 4; ++ni) { acc0[mi][ni] = z; acc1[mi][ni] = z; acc2[mi][ni] = z; }
  gemm_phase_legacy(x, M0, Win, N0, 1024, sA, sB, tid, acc0);
  gemm_phase_legacy(cpt, M0, Wci, N0, 1000, sA, sB, tid, acc1);
#pragma unroll
  for (int mi = 0; mi < 2; ++mi)
#pragma unroll
    for (int ni = 0; ni < 4; ++ni) { acc0[mi][ni] = acc0[mi][ni] * acc1[mi][ni]; acc1[mi][ni] = z; }
  gemm_phase_legacy(h, M0, Wst, N0, 1024, sA, sB, tid, acc1);
  gemm_phase_legacy(cpt, M0, Wcs, N0, 1000, sA, sB, tid, acc2);
  const int w = tid >> 6, lane = tid & 63, l15 = lane & 15, quad = lane >> 4;
#pragma unroll
  for (int mi = 0; mi < 2; ++mi)
#pragma unroll
    for (int ni = 0; ni < 4; ++ni)
#pragma unroll
      for (int r = 0; r < 4; ++r) {
        const float e = acc0[mi][ni][r] + acc1[mi][ni][r] * acc2[mi][ni][r];
        const float s = 1.f / (1.f + __expf(-e));
        const int row = M0 + w * 32 + mi * 16 + quad * 4 + r;
        const int col = N0 + ni * 16 + l15;
        hidden[(size_t)row * 4096 + col] = (bf16_t)s;
      }
}

__global__ __launch_bounds__(THREADS)
void scn_combine(const bf16_t* __restrict__ hidden, const float* __restrict__ cs,
                 float* __restrict__ out)
{
  const int t = blockIdx.x * THREADS + threadIdx.x;
  const size_t idx = (size_t)t * 8;
  const size_t b = idx >> 10, col = idx & 1023;
  const size_t hb = b * 4096 + col;
  const bf16x8 vi = *(const bf16x8*)(hidden + hb);
  const bf16x8 vf = *(const bf16x8*)(hidden + hb + 1024);
  const bf16x8 vo = *(const bf16x8*)(hidden + hb + 2048);
  const bf16x8 vc = *(const bf16x8*)(hidden + hb + 3072);
  const float4 a = *(const float4*)(cs + idx);
  const float4 d = *(const float4*)(cs + idx + 4);
  const float cv[8] = {a.x, a.y, a.z, a.w, d.x, d.y, d.z, d.w};
  float ht[8], ct[8];
#pragma unroll
  for (int e = 0; e < 8; ++e) {
    ct[e] = (float)vi[e] * (float)vc[e] + (float)vf[e] * cv[e];
    ht[e] = (float)vo[e] * tanhf(ct[e]);
  }
  *(float4*)(out + idx)     = make_float4(ht[0], ht[1], ht[2], ht[3]);
  *(float4*)(out + idx + 4) = make_float4(ht[4], ht[5], ht[6], ht[7]);
  float* outc = out + (1u << 20);
  *(float4*)(outc + idx)     = make_float4(ct[0], ct[1], ct[2], ct[3]);
  *(float4*)(outc + idx + 4) = make_float4(ct[4], ct[5], ct[6], ct[7]);
}

extern "C" void kernel_launch(void* const* d_in, const int* in_sizes, int n_in,
                              void* d_out, int out_size, void* d_ws, size_t ws_size,
                              hipStream_t stream) {
  (void)in_sizes; (void)n_in; (void)out_size;
  const float* x   = (const float*)d_in[0];
  const float* h   = (const float*)d_in[1];
  const float* cst = (const float*)d_in[2];
  const float* cpt = (const float*)d_in[3];
  const float* Win = (const float*)d_in[4];
  const float* Wst = (const float*)d_in[5];
  const float* Wci = (const float*)d_in[6];
  const float* Wcs = (const float*)d_in[7];
  float* out = (float*)d_out;
  const size_t MB = 1u << 20;

  if (ws_size >= 38 * MB) {
    char* ws = (char*)d_ws;
    bf16_t* xb   = (bf16_t*)(ws);            // 2 MiB
    bf16_t* hbuf = (bf16_t*)(ws + 2 * MB);   // 2 MiB
    bf16_t* cb   = (bf16_t*)(ws + 4 * MB);   // 2 MiB (K padded)
    bf16_t* Winb = (bf16_t*)(ws + 6 * MB);   // 8 MiB
    bf16_t* Wstb = (bf16_t*)(ws + 14 * MB);  // 8 MiB
    bf16_t* Wcib = (bf16_t*)(ws + 22 * MB);  // 8 MiB (K padded)
    bf16_t* Wcsb = (bf16_t*)(ws + 30 * MB);  // 8 MiB (K padded)
    conv_all<<<5120 + 4608, THREADS, 0, stream>>>(x, h, Win, Wst, cpt, Wci, Wcs,
                                                  xb, hbuf, Winb, Wstb, cb, Wcib, Wcsb);
    dim3 grid(64, 8);   // 64 gate-col groups (16 cols x 4 gates) x 8 row tiles
    scn_gemm_fast3<<<grid, THREADS, 0, stream>>>(xb, hbuf, cb, Winb, Wstb, Wcib, Wcsb,
                                                 cst, out);
  } else {
    bf16_t* hidden = (bf16_t*)((char*)d_ws + 256);
    dim3 grid(4096 / 64, 1024 / 128);
    scn_gemm_legacy<<<grid, THREADS, 0, stream>>>(
        (const char*)x, (const char*)h, (const char*)cpt,
        (const char*)Win, (const char*)Wst, (const char*)Wci, (const char*)Wcs, hidden);
    scn_combine<<<(1024 * 1024 / 8) / THREADS, THREADS, 0, stream>>>(hidden, cst, out);
  }
}